// Round 5
// baseline (637.522 us; speedup 1.0000x reference)
//
#include <hip/hip_runtime.h>
#include <hip/hip_bf16.h>

// ---------------------------------------------------------------------------
// KV-cached MHA, MI355X. Round 5:
//  * gemm2 replaces gemm8 for BOTH projections: 2-wave (128-thr) blocks,
//    BM=128 x BN=128 x BK=32, wave-tile 128x64 (12 ds_read per 32 MFMA =
//    0.375 KB/MFMA reuse), ring-of-3 LDS regions (48 KB static) -> 3
//    blocks/CU co-resident (cross-block async overlap, small barrier scope).
//    qkv grid 1536 = exactly 2 rounds at 3/CU (no tail); out grid 512 = 2/CU.
//    Uniform 8 async16/wave per tile -> per-wave vmcnt(8) counting.
//    Subtile swizzle + phase order carried verbatim from round 3/4
//    (measured 0 bank conflicts).
//  * prep, attn_k unchanged from round 4.
// ---------------------------------------------------------------------------

typedef __bf16 bf16x8 __attribute__((ext_vector_type(8)));
typedef unsigned short u16x8 __attribute__((ext_vector_type(8)));
typedef float  f32x4  __attribute__((ext_vector_type(4)));
typedef unsigned int u32;

#define MFMA16(a, b, c) __builtin_amdgcn_mfma_f32_16x16x32_bf16((a), (b), (c), 0, 0, 0)

__device__ __forceinline__ void async16(__bf16* lds_p, const __bf16* g) {
    __builtin_amdgcn_global_load_lds(
        (__attribute__((address_space(1))) void*)g,
        (__attribute__((address_space(3))) void*)lds_p, 16, 0, 0);
}

// ---------------------------------------------------------------------------
// prep: one grid-stride BW pass (unchanged from round 4).
// ---------------------------------------------------------------------------
__global__ __launch_bounds__(256) void prep(
    const float* __restrict__ q, const float* __restrict__ k, const float* __restrict__ v,
    const float* __restrict__ wq, const float* __restrict__ wk,
    const float* __restrict__ wv, const float* __restrict__ wo,
    const float* __restrict__ ck, const float* __restrict__ cv,
    float* __restrict__ nk, float* __restrict__ nv,
    __bf16* __restrict__ dq, __bf16* __restrict__ dk, __bf16* __restrict__ dv,
    __bf16* __restrict__ dwq, __bf16* __restrict__ dwk,
    __bf16* __restrict__ dwv, __bf16* __restrict__ dwo,
    __bf16* __restrict__ ckb, __bf16* __restrict__ cvb) {
    const int nthreads = gridDim.x * blockDim.x;
    for (int i = blockIdx.x * blockDim.x + threadIdx.x; i < 7340032; i += nthreads) {
        if (i < 2097152) {
            const int sel = i >> 20;
            const int j = i & 1048575;
            const int dh8 = j & 15;
            const int t = (j >> 4) & 1023;
            const int h = (j >> 14) & 15;
            const int b = j >> 18;
            const float* src = sel ? cv : ck;
            float* dst = sel ? nv : nk;
            __bf16* dstb = sel ? cvb : ckb;
            const size_t si = ((size_t)(b << 10) + t) * 2048 + (h << 7) + (dh8 << 3);
            const size_t di = ((size_t)b << 22) + ((size_t)h << 18) + (t << 7) + (dh8 << 3);
            const size_t bi = (((size_t)(b * 16 + h) * 1024 + t) << 7) + (dh8 << 3);
            const f32x4 x0 = *(const f32x4*)&src[si];
            const f32x4 x1 = *(const f32x4*)&src[si + 4];
            *(f32x4*)&dst[di] = x0;
            *(f32x4*)&dst[di + 4] = x1;
            bf16x8 bx;
#pragma unroll
            for (int e = 0; e < 4; e++) {
                bx[e]     = (__bf16)x0[e];
                bx[e + 4] = (__bf16)x1[e];
            }
            *(bf16x8*)&dstb[bi] = bx;
        } else {
            const float* s;
            __bf16* d;
            int off;
            if (i < 5242880) {
                const int ii = i - 2097152;
                const int r = ii >> 20;
                off = ii & 1048575;
                s = (r == 0) ? q : (r == 1) ? k : v;
                d = (r == 0) ? dq : (r == 1) ? dk : dv;
            } else {
                const int ii = i - 5242880;
                const int r = ii >> 19;
                off = ii & 524287;
                s = (r == 0) ? wq : (r == 1) ? wk : (r == 2) ? wv : wo;
                d = (r == 0) ? dwq : (r == 1) ? dwk : (r == 2) ? dwv : dwo;
            }
            const f32x4 x0 = *(const f32x4*)(s + (size_t)off * 8);
            const f32x4 x1 = *(const f32x4*)(s + (size_t)off * 8 + 4);
            bf16x8 o;
#pragma unroll
            for (int j2 = 0; j2 < 4; j2++) {
                o[j2]     = (__bf16)x0[j2];
                o[j2 + 4] = (__bf16)x1[j2];
            }
            *(bf16x8*)(d + (size_t)off * 8) = o;
        }
    }
}

// ---------------------------------------------------------------------------
// gemm2: C[M,2048] = A @ Wseg^T + bias. 128 threads = 2 waves, each owning
// a 128x64 column half of the 128x128 block tile (acc[8][4]).
// LDS = 3 ring regions x 16 KB {A: 8 subtiles 16x32 bf16, B: 8 subtiles};
// subtile chunk-swizzle identical to rounds 3/4 (0 conflicts measured).
// Per K-tile T: {12 ds_read | stage T+2 into region (T+2)%3 (8 async16/wave)
// | vmcnt(8) (per-wave: drains T+1's 8, leaves T+2's 8) | barrier |
// lgkmcnt(0)+sched_barrier | setprio(1) 32 MFMA setprio(0) | barrier}.
// Safety: region (T+2)%3 == (T-1)%3, whose reads completed before the end
// barrier of T-1 (lgkmcnt(0) precedes MFMA precedes barrier).
// MODE 0: C0 fp32 out[4096][2048], grid 512 (2/CU).
// MODE 1: fused QKV over A-concat [12288][2048], grid 1536 (seg = mb>>5):
//   seg 0 -> ws_q bf16 scatter, 1/2 -> new_k/new_v fp32 (t offset +1024).
// ---------------------------------------------------------------------------
template <int MODE>
__global__ __launch_bounds__(128, 2) void gemm2(
    const __bf16* __restrict__ A,
    const __bf16* __restrict__ W0, const __bf16* __restrict__ W1,
    const __bf16* __restrict__ W2,
    const float* __restrict__ bz0, const float* __restrict__ bz1,
    const float* __restrict__ bz2,
    void* __restrict__ C0, float* __restrict__ C1, float* __restrict__ C2) {
    constexpr int K = 2048;
    __shared__ __bf16 lds[3 * 8192];   // 48 KB -> 3 blocks/CU

    const int tid = threadIdx.x;
    const int w = tid >> 6, lane = tid & 63;
    const int g = lane >> 4, c = lane & 15;

    const int lin = blockIdx.x;
    const int nb = lin & 15, mb = lin >> 4;
    const int m0 = mb << 7, n0 = nb << 7;
    const int seg = (MODE == 1) ? (mb >> 5) : 0;
    const __bf16* W = (MODE == 0 || seg == 0) ? W0 : (seg == 1) ? W1 : W2;
    const float* bias = (MODE == 0) ? bz0 : (seg == 0) ? bz0 : (seg == 1) ? bz1 : bz2;

    const __bf16* Ab = A + (size_t)m0 * K;
    const __bf16* Wb = W + (size_t)n0 * K;

    const int srow = lane >> 2;                               // staging row in subtile
    const int sch = (lane & 3) ^ (((lane >> 5) & 1) << 1);    // pre-swizzled chunk
    const int foff = c * 32 + ((g ^ ((c >> 3) << 1)) << 3);   // frag read offset

    f32x4 acc[8][4] = {};

    // stage K-tile T into region rg: wave w stages A-subtiles 4w..4w+3 and
    // B-subtiles 4w..4w+3 -> 8 async16 per wave (uniform).
    auto stg = [&](int T, int rg) {
        const int kof = T * 32 + sch * 8;
#pragma unroll
        for (int s = 0; s < 4; s++) {
            const int st = w * 4 + s;
            async16(&lds[rg * 8192 + st * 512],
                    Ab + (size_t)(st * 16 + srow) * K + kof);
        }
#pragma unroll
        for (int s = 0; s < 4; s++) {
            const int st = w * 4 + s;
            async16(&lds[rg * 8192 + 4096 + st * 512],
                    Wb + (size_t)(st * 16 + srow) * K + kof);
        }
    };

    // prologue: tiles 0,1 -> regions 0,1; require tile 0 complete
    stg(0, 0);
    stg(1, 1);
    asm volatile("s_waitcnt vmcnt(8)" ::: "memory");
    __builtin_amdgcn_s_barrier();

    int rg = 0, rs = 2;
    for (int T = 0; T < 64; T++) {
        const int base = rg * 8192;
        bf16x8 fa[8], fb[4];
#pragma unroll
        for (int mi = 0; mi < 8; mi++)
            fa[mi] = *(const bf16x8*)&lds[base + mi * 512 + foff];
#pragma unroll
        for (int ni = 0; ni < 4; ni++)
            fb[ni] = *(const bf16x8*)&lds[base + 4096 + (w * 4 + ni) * 512 + foff];
        if (T <= 61) {
            stg(T + 2, rs);
            asm volatile("s_waitcnt vmcnt(8)" ::: "memory");
        } else {
            asm volatile("s_waitcnt vmcnt(0)" ::: "memory");
        }
        __builtin_amdgcn_s_barrier();
        asm volatile("s_waitcnt lgkmcnt(0)" ::: "memory");
        __builtin_amdgcn_sched_barrier(0);
        __builtin_amdgcn_s_setprio(1);
#pragma unroll
        for (int mi = 0; mi < 8; mi++)
#pragma unroll
            for (int ni = 0; ni < 4; ni++)
                acc[mi][ni] = MFMA16(fa[mi], fb[ni], acc[mi][ni]);
        __builtin_amdgcn_s_setprio(0);
        __builtin_amdgcn_s_barrier();
        rg = (rg == 2) ? 0 : rg + 1;
        rs = (rs == 2) ? 0 : rs + 1;
    }

    // epilogue: C/D layout col = lane&15 (n), row = (lane>>4)*4 + reg (m)
#pragma unroll
    for (int ni = 0; ni < 4; ni++) {
        const int col = n0 + w * 64 + ni * 16 + c;
        const float bv = bias[col];
        const int h = col >> 7, dh = col & 127;
#pragma unroll
        for (int mi = 0; mi < 8; mi++) {
            const int rowb = m0 + mi * 16 + g * 4;
#pragma unroll
            for (int r = 0; r < 4; r++) {
                const float v = acc[mi][ni][r] + bv;
                if (MODE == 0) {
                    ((float*)C0)[(size_t)(rowb + r) * 2048 + col] = v;
                } else {
                    const int lrow = (rowb + r) & 4095;
                    const int b = lrow >> 10, t = lrow & 1023;
                    if (seg == 0)
                        ((__bf16*)C0)[(((size_t)(b * 16 + h) * 1024) + t) * 128 + dh] = (__bf16)v;
                    else if (seg == 1)
                        C1[(((size_t)(b * 16 + h) * 2048) + 1024 + t) * 128 + dh] = v;
                    else
                        C2[(((size_t)(b * 16 + h) * 2048) + 1024 + t) * 128 + dh] = v;
                }
            }
        }
    }
}

// ---------------------------------------------------------------------------
// Flash attention (unchanged from round 4): KVBLK=32, 4 waves x 16 q-rows,
// bf16 head-major cache mirrors, swizzled Kt/Vt/Pw, balanced dispatch map.
// ---------------------------------------------------------------------------
__global__ __launch_bounds__(256) void attn_k(const __bf16* __restrict__ Qw,
                                              const __bf16* __restrict__ cK,
                                              const __bf16* __restrict__ cV,
                                              __bf16* __restrict__ O) {
    __shared__ __bf16 Kt[32 * 128];
    __shared__ u32 Vt32[128 * 16];
    __shared__ __bf16 Pw[4][16 * 32];

    const int tid = threadIdx.x;
    const int w = tid >> 6;
    const int lane = tid & 63;
    const int g = lane >> 4, c = lane & 15;

    const int lin = blockIdx.x + (blockIdx.y << 4) + (blockIdx.z << 8);
    const int chunk = lin >> 8, idx = lin & 255;
    int qb = idx & 15;
    if (chunk & 1) qb = 15 - qb;
    const int bh = (idx >> 4) + (chunk << 4);
    const int b = bh >> 4, h = bh & 15;
    const int q0 = qb << 6;
    const float inv_scale = 0.08838834764831845f; // 1/sqrt(128)

    const __bf16* qbase = Qw + (((size_t)(b * 16 + h) * 1024) + q0 + w * 16) * 128;
    bf16x8 qf[4];
#pragma unroll
    for (int dc = 0; dc < 4; dc++)
        qf[dc] = *(const bf16x8*)&qbase[c * 128 + dc * 32 + g * 8];

    f32x4 accO[8] = {};
    float m_run[4], l_run[4];
#pragma unroll
    for (int r = 0; r < 4; r++) { m_run[r] = -1e30f; l_run[r] = 0.0f; }

    const int trips = (q0 >> 5) + 2;
    const __bf16* kb = cK + (size_t)(b * 16 + h) * 1024 * 128;
    const __bf16* vb = cV + (size_t)(b * 16 + h) * 1024 * 128;

    const int skey = tid >> 3, sdh = (tid & 7) * 16;
    const int kp = tid >> 4, db = tid & 15;
    const int vcol = (((kp >> 2) ^ (db & 3)) << 2) | (kp & 3);

    for (int kt = 0; kt < trips; kt++) {
        const int k0 = kt * 32;
        const bf16x8 k_lo = *(const bf16x8*)&kb[(size_t)(k0 + skey) * 128 + sdh];
        const bf16x8 k_hi = *(const bf16x8*)&kb[(size_t)(k0 + skey) * 128 + sdh + 8];
        const bf16x8 v0 = *(const bf16x8*)&vb[(size_t)(k0 + 2 * kp) * 128 + db * 8];
        const bf16x8 v1 = *(const bf16x8*)&vb[(size_t)(k0 + 2 * kp + 1) * 128 + db * 8];
        __syncthreads();   // prior iteration's Kt/Vt reads complete
        {
            const int ss = skey & 7, ch0 = (tid & 7) * 2;
            *(bf16x8*)&Kt[skey * 128 + ((ch0 ^ ss) << 3)]       = k_lo;
            *(bf16x8*)&Kt[skey * 128 + (((ch0 + 1) ^ ss) << 3)] = k_hi;
        }
        {
            const u16x8 pa = __builtin_bit_cast(u16x8, v0);
            const u16x8 pb = __builtin_bit_cast(u16x8, v1);
#pragma unroll
            for (int j = 0; j < 8; j++)
                Vt32[(db * 8 + j) * 16 + vcol] = (u32)pa[j] | ((u32)pb[j] << 16);
        }
        __syncthreads();   // staging visible

        f32x4 s_acc[2] = {};
#pragma unroll
        for (int nt = 0; nt < 2; nt++) {
            const int krow = nt * 16 + c;
            const int ks = krow & 7;
#pragma unroll
            for (int dc = 0; dc < 4; dc++) {
                const bf16x8 kf =
                    *(const bf16x8*)&Kt[krow * 128 + (((dc * 4 + g) ^ ks) << 3)];
                s_acc[nt] = MFMA16(qf[dc], kf, s_acc[nt]);
            }
        }

        float p[2][4], alpha[4];
#pragma unroll
        for (int r = 0; r < 4; r++) {
            const int qrow = q0 + w * 16 + g * 4 + r;
            float s0 = (k0 + c      <= qrow) ? s_acc[0][r] * inv_scale : -1e30f;
            float s1 = (k0 + 16 + c <= qrow) ? s_acc[1][r] * inv_scale : -1e30f;
            float rm = fmaxf(s0, s1);
            rm = fmaxf(rm, __shfl_xor(rm, 1));
            rm = fmaxf(rm, __shfl_xor(rm, 2));
            rm = fmaxf(rm, __shfl_xor(rm, 4));
            rm = fmaxf(rm, __shfl_xor(rm, 8));
            const float mnew = fmaxf(m_run[r], rm);
            alpha[r] = __expf(m_run[r] - mnew);
            const float p0 = __expf(s0 - mnew);
            const float p1 = __expf(s1 - mnew);
            p[0][r] = p0; p[1][r] = p1;
            float ps = p0 + p1;
            ps += __shfl_xor(ps, 1);
            ps += __shfl_xor(ps, 2);
            ps += __shfl_xor(ps, 4);
            ps += __shfl_xor(ps, 8);
            l_run[r] = alpha[r] * l_run[r] + ps;
            m_run[r] = mnew;
        }
#pragma unroll
        for (int nt2 = 0; nt2 < 8; nt2++)
#pragma unroll
            for (int r = 0; r < 4; r++)
                accO[nt2][r] *= alpha[r];

#pragma unroll
        for (int nt = 0; nt < 2; nt++)
#pragma unroll
            for (int r = 0; r < 4; r++)
                Pw[w][(g * 4 + r) * 32 + ((((nt << 1) | (c >> 3)) ^ g) << 3) + (c & 7)] =
                    (__bf16)p[nt][r];
        asm volatile("s_waitcnt lgkmcnt(0)" ::: "memory");
        __builtin_amdgcn_sched_barrier(0);

        const bf16x8 pf = *(const bf16x8*)&Pw[w][c * 32 + ((g ^ ((c >> 2) & 3)) << 3)];
#pragma unroll
        for (int nt2 = 0; nt2 < 8; nt2++) {
            const int vrow = nt2 * 16 + c;
            const bf16x8 vf = *(const bf16x8*)&(
                (const __bf16*)Vt32)[vrow * 32 + ((g ^ ((vrow >> 3) & 3)) << 3)];
            accO[nt2] = MFMA16(pf, vf, accO[nt2]);
        }
    }

#pragma unroll
    for (int nt2 = 0; nt2 < 8; nt2++)
#pragma unroll
        for (int r = 0; r < 4; r++) {
            const float v = accO[nt2][r] / l_run[r];
            const int row = b * 1024 + q0 + w * 16 + g * 4 + r;
            const int col = h * 128 + nt2 * 16 + c;
            O[(size_t)row * 2048 + col] = (__bf16)v;
        }
}

// ---------------------------------------------------------------------------
extern "C" void kernel_launch(void* const* d_in, const int* in_sizes, int n_in,
                              void* d_out, int out_size, void* d_ws, size_t ws_size,
                              hipStream_t stream) {
    const float* query       = (const float*)d_in[0];
    const float* key         = (const float*)d_in[1];
    const float* value       = (const float*)d_in[2];
    const float* cache_key   = (const float*)d_in[3];
    const float* cache_value = (const float*)d_in[4];
    const float* Wq = (const float*)d_in[5];
    const float* bq = (const float*)d_in[6];
    const float* Wk = (const float*)d_in[7];
    const float* bk = (const float*)d_in[8];
    const float* Wv = (const float*)d_in[9];
    const float* bv = (const float*)d_in[10];
    const float* Wo = (const float*)d_in[11];
    const float* bo = (const float*)d_in[12];

    float* out   = (float*)d_out;              // [4096][2048] fp32
    float* new_k = out + 8388608;              // [B][H][2048][128] fp32
    float* new_v = out + 25165824;

    // workspace (bf16 elems): q_bf/k_bf/v_bf MUST be contiguous (A-concat)
    __bf16* p = (__bf16*)d_ws;
    __bf16* ws_q    = p; p += 8388608;         // [b][h][1024][128]
    __bf16* ws_attn = p; p += 8388608;         // [4096][2048]
    __bf16* q_bf    = p; p += 8388608;         // A-concat rows 0..4095
    __bf16* k_bf    = p; p += 8388608;         //               4096..8191
    __bf16* v_bf    = p; p += 8388608;         //               8192..12287
    __bf16* wq_bf   = p; p += 4194304;
    __bf16* wk_bf   = p; p += 4194304;
    __bf16* wv_bf   = p; p += 4194304;
    __bf16* wo_bf   = p; p += 4194304;
    __bf16* ck_bf   = p; p += 8388608;         // [b][h][1024][128] head-major
    __bf16* cv_bf   = p;

    prep<<<4096, 256, 0, stream>>>(query, key, value, Wq, Wk, Wv, Wo,
                                   cache_key, cache_value, new_k, new_v,
                                   q_bf, k_bf, v_bf, wq_bf, wk_bf, wv_bf, wo_bf,
                                   ck_bf, cv_bf);
    gemm2<1><<<1536, 128, 0, stream>>>(q_bf, wq_bf, wk_bf, wv_bf,
                                       bq, bk, bv, ws_q, new_k, new_v);
    attn_k<<<dim3(16, 16, 4), 256, 0, stream>>>(ws_q, ck_bf, cv_bf, ws_attn);
    gemm2<0><<<512, 128, 0, stream>>>(ws_attn, wo_bf, nullptr, nullptr,
                                      bo, nullptr, nullptr, out, nullptr, nullptr);
}